// Round 1
// baseline (279.093 us; speedup 1.0000x reference)
//
#include <hip/hip_runtime.h>

// OctVolSynth: element-wise over 256^3 volume.
//   scaling = lut[label]; v = scaling*texture; v = (v==0) ? 1 : v;
//   out0 = parenchyma * v;  out1 = (label != 0) ? 1.0f : 0.0f
//
// History: R1 serial 98us / R3 phases 108 / R4 persistent 107 / R5 sched_barrier
// 98us, VGPR=32 -- the barrier did NOT hold (48+ data regs required, 32 seen),
// so every round so far ran ~2 loads in flight per wave. All pipes idle
// (VALUBusy 3.3%, HBM 30%), so R6 forces 12 loads/wave in flight with inline
// asm the scheduler cannot sink: 12x global_load_dwordx4 (volatile, order
// pinned), one s_waitcnt vmcnt(0), then sched_barrier(0) so consumers cannot
// hoist above the wait (rule #18). SADDR addressing: one shared 32-bit voffset
// + SGPR base per stream, offset:{0,1024,2048,3072} immediates -> each load is
// a fully coalesced 1KB wave access; wave covers 4KB contiguous per stream.

#define N_ELEMS (256 * 256 * 256)
#define LUT_SIZE 302
#define BLOCK 256
#define CHUNKS 4   // 4 float4 chunks per thread per stream -> 16 elems/thread

typedef float vfloat4 __attribute__((ext_vector_type(4)));
typedef int   vint4   __attribute__((ext_vector_type(4)));

// Volatile so the 12 loads keep their mutual program order and cannot be sunk
// past the waitcnt. Results are NOT tracked by the compiler's vmcnt insertion,
// hence the manual s_waitcnt below.
#define GLOAD(dst, off, base, imm)                                   \
  asm volatile("global_load_dwordx4 %0, %1, %2 offset:" #imm         \
               : "=&v"(dst) : "v"(off), "s"(base))

__global__ __launch_bounds__(BLOCK, 4) void octvolsynth_kernel(
    const int* __restrict__ labels,
    const float* __restrict__ parenchyma,
    const float* __restrict__ texture,
    const float* __restrict__ lut,
    float* __restrict__ out)
{
    __shared__ float s_lut[LUT_SIZE];
    for (int i = threadIdx.x; i < LUT_SIZE; i += BLOCK) s_lut[i] = lut[i];
    __syncthreads();   // also drains vmcnt -> our manual counting starts at 0

    const unsigned wid  = threadIdx.x >> 6;
    const unsigned lane = threadIdx.x & 63;
    // byte offset into each stream; each wave owns 4 contiguous KB
    const unsigned off = blockIdx.x * (BLOCK * CHUNKS * 16u)
                       + wid * (CHUNKS * 64u * 16u)
                       + lane * 16u;

    // ---- load phase: 12 independent loads, guaranteed in flight ----
    vint4   l0, l1, l2, l3;
    vfloat4 p0, p1, p2, p3, x0, x1, x2, x3;
    GLOAD(l0, off, labels,     0);
    GLOAD(l1, off, labels,     1024);
    GLOAD(l2, off, labels,     2048);
    GLOAD(l3, off, labels,     3072);
    GLOAD(p0, off, parenchyma, 0);
    GLOAD(p1, off, parenchyma, 1024);
    GLOAD(p2, off, parenchyma, 2048);
    GLOAD(p3, off, parenchyma, 3072);
    GLOAD(x0, off, texture,    0);
    GLOAD(x1, off, texture,    1024);
    GLOAD(x2, off, texture,    2048);
    GLOAD(x3, off, texture,    3072);

    asm volatile("s_waitcnt vmcnt(0)");
    __builtin_amdgcn_sched_barrier(0);  // consumers must not hoist above the wait

    // ---- consume phase: gather, compute, store ----
    const unsigned fidx = off >> 4;          // float4 index; chunk stride = 64
    vfloat4* __restrict__ o4 = (vfloat4*)out;
    vfloat4* __restrict__ m4 = (vfloat4*)(out + N_ELEMS);

#define DO_CHUNK(L, P, X, c) do {                                    \
    float v0 = s_lut[(L).x] * (X).x;                                 \
    float v1 = s_lut[(L).y] * (X).y;                                 \
    float v2 = s_lut[(L).z] * (X).z;                                 \
    float v3 = s_lut[(L).w] * (X).w;                                 \
    vfloat4 fv, mv;                                                  \
    fv.x = (P).x * ((v0 == 0.0f) ? 1.0f : v0);                       \
    fv.y = (P).y * ((v1 == 0.0f) ? 1.0f : v1);                       \
    fv.z = (P).z * ((v2 == 0.0f) ? 1.0f : v2);                       \
    fv.w = (P).w * ((v3 == 0.0f) ? 1.0f : v3);                       \
    mv.x = ((L).x != 0) ? 1.0f : 0.0f;                               \
    mv.y = ((L).y != 0) ? 1.0f : 0.0f;                               \
    mv.z = ((L).z != 0) ? 1.0f : 0.0f;                               \
    mv.w = ((L).w != 0) ? 1.0f : 0.0f;                               \
    o4[fidx + (c) * 64] = fv;                                        \
    m4[fidx + (c) * 64] = mv;                                        \
} while (0)

    DO_CHUNK(l0, p0, x0, 0);
    DO_CHUNK(l1, p1, x1, 1);
    DO_CHUNK(l2, p2, x2, 2);
    DO_CHUNK(l3, p3, x3, 3);

#undef DO_CHUNK
}

extern "C" void kernel_launch(void* const* d_in, const int* in_sizes, int n_in,
                              void* d_out, int out_size, void* d_ws, size_t ws_size,
                              hipStream_t stream) {
    const int*   labels     = (const int*)d_in[0];
    const float* parenchyma = (const float*)d_in[1];
    const float* texture    = (const float*)d_in[2];
    const float* lut        = (const float*)d_in[3];
    float* out = (float*)d_out;

    // bytes per stream per block = BLOCK*CHUNKS*16 = 16 KB; 64 MiB / 16 KB = 4096
    const int grid = (N_ELEMS * 4) / (BLOCK * CHUNKS * 16);   // 4096, no tail
    octvolsynth_kernel<<<grid, BLOCK, 0, stream>>>(labels, parenchyma, texture, lut, out);
}

// Round 2
// 278.440 us; speedup vs baseline: 1.0023x; 1.0023x over previous
//
#include <hip/hip_runtime.h>

// OctVolSynth: element-wise over 256^3 volume.
//   scaling = lut[label]; v = scaling*texture; v = (v==0) ? 1 : v;
//   out0 = parenchyma * v;  out1 = (label != 0) ? 1.0f : 0.0f
//
// R5 sched_barrier: 98us VGPR=32 (barrier defeated). R6 asm-forced 12-load
// burst: counters came back BIT-IDENTICAL to R5 (VGPR=32 -- impossible with
// 48 live asm outputs) => stale measurement suspected. R7 fingerprints itself:
// BLOCK=512 (Workgroup_Size), ~48 VGPR structure. MLP experiment redesigned:
// 6 asm loads in flight/wave (24 data VGPRs, stays in the <=64 VGPR bin =>
// 8 waves/SIMD retained), progressive consume via partial vmcnt waits
// (vmcnt in-order retire, m135; stores counted explicitly; ALL vmem is asm
// so compiler ops can't corrupt the counts; sched_barrier(0) after each wait
// per rule #18).

#define N_ELEMS (256 * 256 * 256)
#define LUT_SIZE 302
#define BLOCK 512
#define CHUNKS 2   // float4 chunks per thread per stream -> 8 elems/thread

typedef float vfloat4 __attribute__((ext_vector_type(4)));
typedef int   vint4   __attribute__((ext_vector_type(4)));

// Loads: volatile, mutual program order pinned, results untracked by the
// compiler's waitcnt logic (manual s_waitcnt below). SADDR form: 32-bit
// voffset + SGPR-pair base, 13-bit imm offset.
#define GLOAD(dst, off, base, imm)                                    \
  asm volatile("global_load_dwordx4 %0, %1, %2 offset:" #imm          \
               : "=&v"(dst) : "v"(off), "s"(base))

#define GSTORE(src, off, base, imm)                                   \
  asm volatile("global_store_dwordx4 %0, %1, %2 offset:" #imm         \
               :: "v"(off), "v"(src), "s"(base) : "memory")

#define WAITCNT_VM(n)                                                 \
  do {                                                                \
    asm volatile("s_waitcnt vmcnt(" #n ")" ::: "memory");             \
    __builtin_amdgcn_sched_barrier(0);                                \
  } while (0)

__global__ __launch_bounds__(BLOCK) void octvolsynth_r7(
    const int* __restrict__ labels,
    const float* __restrict__ parenchyma,
    const float* __restrict__ texture,
    const float* __restrict__ lut,
    float* __restrict__ out)
{
    __shared__ float s_lut[LUT_SIZE];
    for (int i = threadIdx.x; i < LUT_SIZE; i += BLOCK) s_lut[i] = lut[i];
    __syncthreads();   // drains vmcnt -> manual counting starts at 0

    const unsigned wid  = threadIdx.x >> 6;
    const unsigned lane = threadIdx.x & 63;
    // byte offset; each wave owns CHUNKS KB contiguous per stream
    const unsigned off = blockIdx.x * (BLOCK * CHUNKS * 16u)
                       + wid * (CHUNKS * 64u * 16u)
                       + lane * 16u;

    const float* outm = out + N_ELEMS;   // mask plane base

    // ---- issue phase: 6 independent loads, order = (l,p,x) per chunk ----
    vint4   l0, l1;
    vfloat4 p0, p1, x0, x1;
    GLOAD(l0, off, labels,     0);
    GLOAD(p0, off, parenchyma, 0);
    GLOAD(x0, off, texture,    0);
    GLOAD(l1, off, labels,     1024);
    GLOAD(p1, off, parenchyma, 1024);
    GLOAD(x1, off, texture,    1024);

#define DO_CHUNK(L, P, X, imm) do {                                   \
    float v0 = s_lut[(L).x] * (X).x;                                  \
    float v1 = s_lut[(L).y] * (X).y;                                  \
    float v2 = s_lut[(L).z] * (X).z;                                  \
    float v3 = s_lut[(L).w] * (X).w;                                  \
    vfloat4 fv, mv;                                                   \
    fv.x = (P).x * ((v0 == 0.0f) ? 1.0f : v0);                        \
    fv.y = (P).y * ((v1 == 0.0f) ? 1.0f : v1);                        \
    fv.z = (P).z * ((v2 == 0.0f) ? 1.0f : v2);                        \
    fv.w = (P).w * ((v3 == 0.0f) ? 1.0f : v3);                        \
    mv.x = ((L).x != 0) ? 1.0f : 0.0f;                                \
    mv.y = ((L).y != 0) ? 1.0f : 0.0f;                                \
    mv.z = ((L).z != 0) ? 1.0f : 0.0f;                                \
    mv.w = ((L).w != 0) ? 1.0f : 0.0f;                                \
    GSTORE(fv, off, out,  imm);                                       \
    GSTORE(mv, off, outm, imm);                                       \
} while (0)

    // outstanding: 6 loads. wait(3) retires l0,p0,x0.
    WAITCNT_VM(3);
    DO_CHUNK(l0, p0, x0, 0);        // outstanding: 3 loads + 2 stores
    // wait(2) retires the 3 oldest = l1,p1,x1 (in-order).
    WAITCNT_VM(2);
    DO_CHUNK(l1, p1, x1, 1024);     // outstanding: 4 stores; drain at endpgm

#undef DO_CHUNK
}

extern "C" void kernel_launch(void* const* d_in, const int* in_sizes, int n_in,
                              void* d_out, int out_size, void* d_ws, size_t ws_size,
                              hipStream_t stream) {
    const int*   labels     = (const int*)d_in[0];
    const float* parenchyma = (const float*)d_in[1];
    const float* texture    = (const float*)d_in[2];
    const float* lut        = (const float*)d_in[3];
    float* out = (float*)d_out;

    // per block per stream: BLOCK*CHUNKS*16 B = 16 KB -> 64 MiB / 16 KB = 4096
    const int grid = (N_ELEMS * 4) / (BLOCK * CHUNKS * 16);   // 4096, no tail
    octvolsynth_r7<<<grid, BLOCK, 0, stream>>>(labels, parenchyma, texture, lut, out);
}